// Round 11
// baseline (309.382 us; speedup 1.0000x reference)
//
#include <hip/hip_runtime.h>

#define BB 512
#define SS 512
#define TT 78
#define TP 80      // padded tag count
#define NT 128     // 2 waves: wave0 = score chain, wave1 = alpha chain

typedef _Float16 v2h __attribute__((ext_vector_type(2)));

template<int I> struct ic { static constexpr int v = I; };
template<int I, int N, typename F>
__device__ __forceinline__ void sfor(F f) {
    if constexpr (I < N) { f(ic<I>{}); sfor<I + 1, N>(f); }
}

__device__ __forceinline__ unsigned short f16b(float x) {
    return __builtin_bit_cast(unsigned short, (_Float16)x);
}

__global__ __attribute__((amdgpu_flat_work_group_size(NT, NT),
                          amdgpu_waves_per_eu(1, 1)))
void crf_fwd_kernel(const float* __restrict__ em,          // [B,S,T]
                    const unsigned int* __restrict__ mi32, // [B,S]
                    const float* __restrict__ st,
                    const float* __restrict__ en_,
                    const float* __restrict__ tr,          // [T,T]
                    float* __restrict__ out)               // [B]
{
    const int b    = blockIdx.x;
    const int tid  = threadIdx.x;
    const int w    = tid >> 6;            // 0 = score (masked), 1 = alpha
    const int lane = tid & 63;
    const bool has2 = lane < (TT - 64);
    const int  t0  = lane;
    const int  t1c = has2 ? (lane + 64) : (TT - 1);

    __shared__ __align__(16) unsigned short sEh[2][TP];  // E as f16, per chain
    __shared__ float sfin[2];
    __shared__ int sflag;

    // ---- mask layout detection (int32 vs byte bools) ----
    if (tid == 0) sflag = 1;
    __syncthreads();
    { bool ok = true;
      for (int k = tid; k < 512; k += NT) ok = ok && (mi32[k] <= 1u);
      if (!ok) atomicAnd(&sflag, 0); }
    __syncthreads();
    const bool mask_int = (sflag != 0);
    const unsigned char* mi8 = (const unsigned char*)mi32;
    const bool is_alpha = (w == 1);

    // ---- W = exp(trans) as PACKED F16 PAIRS: 80 VGPRs total — fits under
    // the ~132-VGPR allocation cap that fp32 W (160 regs) could never fit.
    unsigned wt0[TP / 2], wt1[TP / 2];   // wt0[p] = {W[2p][t0], W[2p+1][t0]}
    sfor<0, TP / 2>([&](auto P) {
        constexpr int p = decltype(P)::v;
        constexpr int j0 = 2 * p, j1 = 2 * p + 1;
        float a0 = (j0 < TT) ? __expf(tr[j0 * TT + t0])  : 0.f;
        float a1 = (j1 < TT) ? __expf(tr[j1 * TT + t0])  : 0.f;
        float b0 = (j0 < TT) ? __expf(tr[j0 * TT + t1c]) : 0.f;
        float b1 = (j1 < TT) ? __expf(tr[j1 * TT + t1c]) : 0.f;
        unsigned pa = (unsigned)f16b(a0) | ((unsigned)f16b(a1) << 16);
        unsigned pb = (unsigned)f16b(b0) | ((unsigned)f16b(b1) << 16);
        asm volatile("" : "+v"(pa), "+v"(pb));   // anti-remat fence (locals only!)
        wt0[p] = pa; wt1[p] = pb;
    });

    // ---- linear-domain state: E = exp(state - M2*ln2) ----
    const size_t base = (size_t)b * SS * TT;
    float e0 = __expf(st[t0]  + em[base + t0]);
    float e1 = __expf(st[t1c] + em[base + t1c]);
    int M2 = 0;

    if (lane == 14 || lane == 15) sEh[w][64 + lane] = 0;  // pad slots 78,79
    sEh[w][lane] = f16b(e0);
    if (has2) sEh[w][64 + lane] = f16b(e1);

    // prefetch step 1 (exp off the critical path)
    const float* rp = em + base + TT;
    float EmN0 = __expf(rp[t0]);
    float EmN1 = __expf(rp[t1c]);
    unsigned int mk_n = mask_int ? mi32[b * SS + 1]
                                 : (unsigned int)mi8[b * SS + 1];

    for (int i = 1; i < SS; ++i) {
        const float Em0 = EmN0, Em1 = EmN1;
        const unsigned int mki = mk_n;
        if (i + 1 < SS) {
            rp += TT;
            EmN0 = __expf(rp[t0]);
            EmN1 = __expf(rp[t1c]);
            mk_n = mask_int ? mi32[b * SS + i + 1]
                            : (unsigned int)mi8[b * SS + i + 1];
        }
        __builtin_amdgcn_wave_barrier();

        // ---- E vector (80 f16 = 40 pairs) via 10 broadcast b128 reads ----
        const uint4* ep = (const uint4*)sEh[w];
        unsigned xs[TP / 2];
        sfor<0, TP / 8>([&](auto K) {
            constexpr int k = decltype(K)::v;
            uint4 q = ep[k];
            xs[4 * k + 0] = q.x; xs[4 * k + 1] = q.y;
            xs[4 * k + 2] = q.z; xs[4 * k + 3] = q.w;
        });

        // ---- v[t] = sum_j E[j]*W[j][t] : 80 x v_dot2_f32_f16 (builtin) ----
        float a00 = 0.f, a01 = 0.f, c00 = 0.f, c01 = 0.f;
        sfor<0, TP / 2>([&](auto P) {
            constexpr int p = decltype(P)::v;
            v2h x  = __builtin_bit_cast(v2h, xs[p]);
            v2h w0 = __builtin_bit_cast(v2h, wt0[p]);
            v2h w1 = __builtin_bit_cast(v2h, wt1[p]);
            if constexpr ((p & 1) == 0) {
                a00 = __builtin_amdgcn_fdot2(x, w0, a00, false);
                c00 = __builtin_amdgcn_fdot2(x, w1, c00, false);
            } else {
                a01 = __builtin_amdgcn_fdot2(x, w0, a01, false);
                c01 = __builtin_amdgcn_fdot2(x, w1, c01, false);
            }
        });
        float v0 = a00 + a01;   // v at tag t0
        float v1 = c00 + c01;   // v at tag t1

        // ---- renorm by WAVE MAX exponent (exact pow2; keeps f16 in range) ----
        float mx = fmaxf(v0, v1);
        #pragma unroll
        for (int o = 32; o > 0; o >>= 1) mx = fmaxf(mx, __shfl_xor(mx, o));
        int   d2  = (int)((__float_as_uint(mx) >> 23) & 0xFF) - 127;
        float scl = __uint_as_float((unsigned)(127 - d2) << 23);
        float n0 = v0 * scl * Em0;
        float n1 = v1 * scl * Em1;

        const bool upd = is_alpha | (mki != 0);
        e0 = upd ? n0 : e0;
        e1 = upd ? n1 : e1;
        M2 = upd ? M2 + d2 : M2;

        __builtin_amdgcn_wave_barrier();
        sEh[w][lane] = f16b(e0);
        if (has2) sEh[w][64 + lane] = f16b(e1);
    }

    // ---- final: ln(sum_t E[t]*exp(end[t])) + M2*ln2 per chain ----
    float fs = e0 * __expf(en_[t0]);
    if (has2) fs += e1 * __expf(en_[t1c]);
    #pragma unroll
    for (int o = 32; o > 0; o >>= 1) fs += __shfl_xor(fs, o);
    if (lane == 0) sfin[w] = __logf(fs) + (float)M2 * 0.6931471805599453f;
    __syncthreads();
    if (tid == 0) out[b] = sfin[1] - sfin[0];   // partition - score
}

extern "C" void kernel_launch(void* const* d_in, const int* in_sizes, int n_in,
                              void* d_out, int out_size, void* d_ws, size_t ws_size,
                              hipStream_t stream) {
    const float* emissions    = (const float*)d_in[0];
    const unsigned int* mask  = (const unsigned int*)d_in[1];
    const float* start_trans  = (const float*)d_in[2];
    const float* end_trans    = (const float*)d_in[3];
    const float* transitions  = (const float*)d_in[4];
    float* out = (float*)d_out;

    crf_fwd_kernel<<<BB, NT, 0, stream>>>(emissions, mask, start_trans,
                                          end_trans, transitions, out);
}